// Round 13
// baseline (67.763 us; speedup 1.0000x reference)
//
#include <hip/hip_runtime.h>
#include <hip/hip_bf16.h>
#include <hip/hip_cooperative_groups.h>

namespace cg = cooperative_groups;

// StackedPyrHourGlassLoss — round 13: SINGLE cooperative kernel.
// r12 (2 nodes) = 19.0 µs, of which ~14-15 µs is graph-node overhead.
// This round: 1 node. 256 blocks x 256 threads (1 block/CU, co-resident by
// construction), each block grid-strides 15 pbs: parallel validity fetch,
// deterministic serial compaction, heavy pbs processed by all 256 threads,
// per-block 6-float partial -> grid.sync() -> block 0 reduces + writes loss.
// r5/r11 lesson respected: sync participants = 256 (not 3608), via the
// runtime's cooperative-launch barrier, no per-block ad-hoc release chains.

constexpr int NBATCH = 2;
constexpr int EMB = 32;
constexpr int TGTC = 9;      // 1 gt + 8 affinity channels
constexpr int PZ = 5, PY = 15, PX = 15;
constexpr int P = PZ * PY * PX;   // 1125

constexpr int NBLK0 = NBATCH * 4 * 17 * 17;  // 2312
constexpr int NBLK1 = NBATCH * 4 * 9 * 9;    // 648
constexpr int NBLK2 = NBATCH * 4 * 9 * 9;    // 648
constexpr int NBLK_TOT = NBLK0 + NBLK1 + NBLK2;  // 3608

constexpr int GRID = 256;
constexpr int SMAX = (NBLK_TOT + GRID - 1) / GRID;   // 15 pb slots per block

// per-thread partial (num,den) for one patch-block; o strided by 256
template <int Wd, int HWd, int CHd,
          int SH, int SW, int DH, int DW,
          int OFFY, int OFFX>
__device__ __forceinline__
void heavy(const int b, const int i, const int j, const int k, const int c,
           const float* __restrict__ pred, const int* __restrict__ tgt,
           const float* __restrict__ Wm, const float* __restrict__ bv,
           float& num_o, float& den_o)
{
    const int tid = threadIdx.x;
    const int cidx = (2 + i) * HWd + (OFFY + j * SH) * Wd + (OFFX + k * SW);

    // embedding: blockIdx-uniform addresses -> scalar loads
    float ev[EMB];
    #pragma unroll
    for (int e = 0; e < EMB; ++e)
        ev[e] = pred[(b * EMB + e) * CHd + cidx];

    const int* __restrict__ gtb = tgt + b * TGTC * CHd;

    float num = 0.0f, den = 0.0f;
    for (int o = tid; o < P; o += 256) {
        const int pz = o / (PY * PX);
        const int r  = o - pz * (PY * PX);
        const int py = r / PX;
        const int px = r - py * PX;

        float dot = bv[o];
        #pragma unroll
        for (int e = 0; e < EMB; ++e)
            dot = fmaf(ev[e], Wm[e * P + o], dot);
        float pp = __builtin_amdgcn_rcpf(1.0f + __expf(-dot));

        const int zb = i + pz;
        const int yb = j * SH + py * DH;
        const int xb = k * SW + px * DW;
        bool anyz = false, anyd = false;
        #pragma unroll
        for (int wy = 0; wy < DH; ++wy) {
            #pragma unroll
            for (int wx = 0; wx < DW; ++wx) {
                const int g = gtb[zb * HWd + (yb + wy) * Wd + (xb + wx)];
                anyz |= (g == 0);
                anyd |= (g != c);
            }
        }
        float trg = (anyz || !anyd) ? 0.0f : 1.0f;
        if (anyz) pp = 0.0f;

        num = fmaf(pp, trg, num);
        den += pp * pp + trg * trg;
    }
    num_o = num;
    den_o = den;
}

__global__ __launch_bounds__(256)
void coop_kernel(const float* __restrict__ pred0, const int* __restrict__ tgt0,
                 const float* __restrict__ W0, const float* __restrict__ b0,
                 const float* __restrict__ pred1, const int* __restrict__ tgt1,
                 const float* __restrict__ W1, const float* __restrict__ b1,
                 const float* __restrict__ pred2, const int* __restrict__ tgt2,
                 const float* __restrict__ W2, const float* __restrict__ b2,
                 float* __restrict__ partials,    // [GRID][6]
                 float* __restrict__ out)
{
    const int bid = blockIdx.x;
    const int tid = threadIdx.x;

    __shared__ int   s_val[SMAX][5];
    __shared__ int   s_meta[SMAX][6];   // lvl, b, i, j, k, c
    __shared__ int   s_flag[SMAX];
    __shared__ int   s_list[SMAX];
    __shared__ int   s_nv;
    __shared__ float s_acc[6];
    __shared__ float sn[4], sd[4];
    __shared__ float s_fin[4][6];

    if (tid < 6) s_acc[tid] = 0.0f;

    // ---- phase A: parallel validity fetch (one latency round) ----
    if (tid < SMAX * 5) {
        const int s = tid / 5, q = tid % 5;
        const int pb = bid + GRID * s;
        if (pb < NBLK_TOT) {
            int lvl, lb, NBW, NBH, Wd, HWd, CHd, offy, offx, st, affb;
            const int* tg;
            if (pb < NBLK0) {
                lvl = 0; lb = pb; NBW = 17; NBH = 17;
                Wd = 160; HWd = 25600; CHd = 204800;
                offy = 30; offx = 30; st = 6; affb = 5; tg = tgt0;
            } else if (pb < NBLK0 + NBLK1) {
                lvl = 1; lb = pb - NBLK0; NBW = 9; NBH = 9;
                Wd = 80; HWd = 6400; CHd = 51200;
                offy = 15; offx = 15; st = 6; affb = 1; tg = tgt1;
            } else {
                lvl = 2; lb = pb - NBLK0 - NBLK1; NBW = 9; NBH = 9;
                Wd = 40; HWd = 1600; CHd = 12800;
                offy = 7; offx = 7; st = 3; affb = 1; tg = tgt2;
            }
            const int k  = lb % NBW;
            const int t1 = lb / NBW;
            const int j  = t1 % NBH;
            const int t2 = t1 / NBH;
            const int i  = t2 & 3;        // NB0 = 4 at all levels
            const int b  = t2 >> 2;
            const int cidx = (2 + i) * HWd + (offy + j * st) * Wd + (offx + k * st);
            const int ch = (q == 0) ? 0 : (affb + q - 1);
            s_val[s][q] = tg[(b * TGTC + ch) * CHd + cidx];
            if (q == 0) {
                s_meta[s][0] = lvl; s_meta[s][1] = b; s_meta[s][2] = i;
                s_meta[s][3] = j;   s_meta[s][4] = k;
            }
        }
    }
    __syncthreads();
    if (tid < SMAX) {
        const int pb = bid + GRID * tid;
        bool v = false;
        if (pb < NBLK_TOT) {
            const int c = s_val[tid][0];
            v = (c != 0) && s_val[tid][1] && s_val[tid][2]
                         && s_val[tid][3] && s_val[tid][4];
            s_meta[tid][5] = c;
        }
        s_flag[tid] = v;
    }
    __syncthreads();
    if (tid == 0) {                      // deterministic compaction
        int n = 0;
        #pragma unroll
        for (int s = 0; s < SMAX; ++s)
            if (s_flag[s]) s_list[n++] = s;
        s_nv = n;
    }
    __syncthreads();

    // ---- phase B: heavy pbs, all 256 threads each ----
    const int nv = s_nv;
    for (int v = 0; v < nv; ++v) {
        const int s   = s_list[v];
        const int lvl = s_meta[s][0], b = s_meta[s][1], i = s_meta[s][2];
        const int j   = s_meta[s][3], k = s_meta[s][4], c = s_meta[s][5];

        float num, den;
        if (lvl == 0)
            heavy<160, 25600, 204800, 6, 6, 4, 4, 30, 30>(
                b, i, j, k, c, pred0, tgt0, W0, b0, num, den);
        else if (lvl == 1)
            heavy<80, 6400, 51200, 6, 6, 2, 2, 15, 15>(
                b, i, j, k, c, pred1, tgt1, W1, b1, num, den);
        else
            heavy<40, 1600, 12800, 3, 3, 1, 1, 7, 7>(
                b, i, j, k, c, pred2, tgt2, W2, b2, num, den);

        #pragma unroll
        for (int off = 32; off > 0; off >>= 1) {
            num += __shfl_xor(num, off);
            den += __shfl_xor(den, off);
        }
        if ((tid & 63) == 0) { sn[tid >> 6] = num; sd[tid >> 6] = den; }
        __syncthreads();
        if (tid == 0) {
            s_acc[2 * lvl]     += sn[0] + sn[1] + sn[2] + sn[3];
            s_acc[2 * lvl + 1] += sd[0] + sd[1] + sd[2] + sd[3];
        }
        __syncthreads();
    }

    if (tid < 6) partials[bid * 6 + tid] = s_acc[tid];

    cg::this_grid().sync();

    // ---- block 0: final reduce of [GRID][6] ----
    if (bid == 0) {
        const float* p = partials + tid * 6;    // one row per thread
        float n0 = p[0], d0 = p[1], n1 = p[2], d1 = p[3], n2 = p[4], d2 = p[5];

        #pragma unroll
        for (int off = 32; off > 0; off >>= 1) {
            n0 += __shfl_xor(n0, off);  d0 += __shfl_xor(d0, off);
            n1 += __shfl_xor(n1, off);  d1 += __shfl_xor(d1, off);
            n2 += __shfl_xor(n2, off);  d2 += __shfl_xor(d2, off);
        }
        if ((tid & 63) == 0) {
            const int w = tid >> 6;
            s_fin[w][0] = n0; s_fin[w][1] = d0; s_fin[w][2] = n1;
            s_fin[w][3] = d1; s_fin[w][4] = n2; s_fin[w][5] = d2;
        }
        __syncthreads();
        if (tid == 0) {
            float a[6];
            #pragma unroll
            for (int q = 0; q < 6; ++q)
                a[q] = s_fin[0][q] + s_fin[1][q] + s_fin[2][q] + s_fin[3][q];
            float loss = 0.0f;
            loss += -2.0f * a[0] / fmaxf(a[1], 1e-6f);
            loss += -2.0f * a[2] / fmaxf(a[3], 1e-6f);
            loss += -2.0f * a[4] / fmaxf(a[5], 1e-6f);
            out[0] = loss;
        }
    }
}

extern "C" void kernel_launch(void* const* d_in, const int* in_sizes, int n_in,
                              void* d_out, int out_size, void* d_ws, size_t ws_size,
                              hipStream_t stream)
{
    const float* pred0 = (const float*)d_in[0];
    const int*   tgt0  = (const int*)  d_in[1];
    const float* W0    = (const float*)d_in[2];
    const float* b0    = (const float*)d_in[3];
    const float* pred1 = (const float*)d_in[4];
    const int*   tgt1  = (const int*)  d_in[5];
    const float* W1    = (const float*)d_in[6];
    const float* b1    = (const float*)d_in[7];
    const float* pred2 = (const float*)d_in[8];
    const int*   tgt2  = (const int*)  d_in[9];
    const float* W2    = (const float*)d_in[10];
    const float* b2    = (const float*)d_in[11];

    float* out      = (float*)d_out;
    float* partials = (float*)d_ws;    // [256][6] floats, fully rewritten/call

    void* args[] = {
        (void*)&pred0, (void*)&tgt0, (void*)&W0, (void*)&b0,
        (void*)&pred1, (void*)&tgt1, (void*)&W1, (void*)&b1,
        (void*)&pred2, (void*)&tgt2, (void*)&W2, (void*)&b2,
        (void*)&partials, (void*)&out
    };
    hipLaunchCooperativeKernel((const void*)coop_kernel,
                               dim3(GRID), dim3(256), args, 0, stream);
}

// Round 14
// 29.240 us; speedup vs baseline: 2.3175x; 2.3175x over previous
//
#include <hip/hip_runtime.h>
#include <hip/hip_bf16.h>

// StackedPyrHourGlassLoss — round 14: sentinel-poll fusion.
// r5/r11/r13 (triple-confirmed): ANY cross-block ordering op (RMW chain,
// release fence, runtime grid.sync) costs 30-60 µs on gfx950. This design
// uses NO ordering: each partial slot is written exactly once via RELAXED
// agent-scope atomic stores (distinct addresses — visibility without
// ordering); a memset node pre-fills the array with 0xFFFFFFFF (-NaN,
// unreachable by finite num/den); one poller block spin-reads until no
// sentinel remains, then reduces in place (r12 finalize logic) and writes
// the loss. Graph = [memset 28.9 KB] + [kernel 3609 blocks].

constexpr int NBATCH = 2;
constexpr int EMB = 32;
constexpr int TGTC = 9;      // 1 gt + 8 affinity channels
constexpr int PZ = 5, PY = 15, PX = 15;
constexpr int P = PZ * PY * PX;   // 1125

constexpr int NBLK0 = NBATCH * 4 * 17 * 17;  // 2312
constexpr int NBLK1 = NBATCH * 4 * 9 * 9;    // 648
constexpr int NBLK2 = NBATCH * 4 * 9 * 9;    // 648
constexpr int NBLK_TOT = NBLK0 + NBLK1 + NBLK2;  // 3608

constexpr unsigned int SENT = 0xFFFFFFFFu;   // -NaN bit pattern

__device__ __forceinline__ void slot_store(float* p, float v)
{
    __hip_atomic_store(p, v, __ATOMIC_RELAXED, __HIP_MEMORY_SCOPE_AGENT);
}

template <int D, int H, int W,
          int NB0, int NBH, int NBW,
          int SH, int SW,
          int DH, int DWIN,
          int OFFZ, int OFFY, int OFFX,
          int AFFB>
__device__ __forceinline__
void level_body(const int lbid,
                const float* __restrict__ pred,
                const int* __restrict__ tgt,
                const float* __restrict__ Wm,
                const float* __restrict__ bv,
                float* __restrict__ partials)
{
    const int tid = threadIdx.x;

    int k  = lbid % NBW;
    int t1 = lbid / NBW;
    int j  = t1 % NBH;
    int t2 = t1 / NBH;
    int i  = t2 % NB0;
    int b  = t2 / NB0;

    const int HW = H * W;
    const int CH = D * HW;
    const int zc = OFFZ + i;           // z-stride is 1 at all levels
    const int yc = OFFY + j * SH;
    const int xc = OFFX + k * SW;
    const int cidx = zc * HW + yc * W + xc;

    // validity: blockIdx-uniform addresses -> scalar loads, no LDS/barrier
    const int c = tgt[b * TGTC * CH + cidx];
    bool allaff = true;
    #pragma unroll
    for (int ch = 0; ch < 4; ++ch)
        allaff &= (tgt[(b * TGTC + AFFB + ch) * CH + cidx] != 0);
    const bool valid = (c != 0) && allaff;

    if (!valid) {
        if (tid == 0) {
            slot_store(&partials[2 * lbid],     0.0f);
            slot_store(&partials[2 * lbid + 1], 0.0f);
        }
        return;                        // no barrier on the 94% path
    }

    // embedding: 32 uniform loads -> scalar registers
    float ev[EMB];
    #pragma unroll
    for (int e = 0; e < EMB; ++e)
        ev[e] = pred[(b * EMB + e) * CH + cidx];

    const int* __restrict__ gtb = tgt + b * TGTC * CH;  // gt channel

    float num = 0.0f, den = 0.0f;
    for (int o = tid; o < P; o += 256) {
        const int pz = o / (PY * PX);
        const int r  = o - pz * (PY * PX);
        const int py = r / PX;
        const int px = r - py * PX;

        float dot = bv[o];
        #pragma unroll
        for (int e = 0; e < EMB; ++e)
            dot = fmaf(ev[e], Wm[e * P + o], dot);
        // fast sigmoid (rel err ~1e-7; threshold 4.7e-2)
        float pp = __builtin_amdgcn_rcpf(1.0f + __expf(-dot));

        const int zb = i + pz;
        const int yb = j * SH + py * DH;
        const int xb = k * SW + px * DWIN;
        bool anyz = false, anyd = false;
        #pragma unroll
        for (int wy = 0; wy < DH; ++wy) {
            #pragma unroll
            for (int wx = 0; wx < DWIN; ++wx) {
                const int g = gtb[zb * HW + (yb + wy) * W + (xb + wx)];
                anyz |= (g == 0);
                anyd |= (g != c);
            }
        }
        float trg = (anyz || !anyd) ? 0.0f : 1.0f;
        if (anyz) pp = 0.0f;

        num = fmaf(pp, trg, num);
        den += pp * pp + trg * trg;
    }

    #pragma unroll
    for (int off = 32; off > 0; off >>= 1) {
        num += __shfl_xor(num, off);
        den += __shfl_xor(den, off);
    }
    __shared__ float sn[4], sd[4];
    if ((tid & 63) == 0) { sn[tid >> 6] = num; sd[tid >> 6] = den; }
    __syncthreads();
    if (tid == 0) {
        slot_store(&partials[2 * lbid],
                   sn[0] + sn[1] + sn[2] + sn[3]);
        slot_store(&partials[2 * lbid + 1],
                   sd[0] + sd[1] + sd[2] + sd[3]);
    }
}

__global__ __launch_bounds__(256)
void fused_kernel(const float* __restrict__ pred0, const int* __restrict__ tgt0,
                  const float* __restrict__ W0, const float* __restrict__ b0,
                  const float* __restrict__ pred1, const int* __restrict__ tgt1,
                  const float* __restrict__ W1, const float* __restrict__ b1,
                  const float* __restrict__ pred2, const int* __restrict__ tgt2,
                  const float* __restrict__ W2, const float* __restrict__ b2,
                  float* __restrict__ partials,
                  float* __restrict__ out)
{
    const int gb = blockIdx.x;
    const int tid = threadIdx.x;

    if (gb < NBLK0) {
        // lvl0: 8,160,160  nb=(4,17,17) s=6 dws=4 off=(2,30,30) aff 5..8
        level_body<8, 160, 160, 4, 17, 17, 6, 6, 4, 4, 2, 30, 30, 5>(
            gb, pred0, tgt0, W0, b0, partials);
        return;
    } else if (gb < NBLK0 + NBLK1) {
        // lvl1: 8,80,80  nb=(4,9,9) s=6 dws=2 off=(2,15,15) aff 1..4
        level_body<8, 80, 80, 4, 9, 9, 6, 6, 2, 2, 2, 15, 15, 1>(
            gb - NBLK0, pred1, tgt1, W1, b1, partials + 2 * NBLK0);
        return;
    } else if (gb < NBLK_TOT) {
        // lvl2: 8,40,40  nb=(4,9,9) s=3 dws=1 off=(2,7,7) aff 1..4
        level_body<8, 40, 40, 4, 9, 9, 3, 3, 1, 1, 2, 7, 7, 1>(
            gb - NBLK0 - NBLK1, pred2, tgt2, W2, b2,
            partials + 2 * (NBLK0 + NBLK1));
        return;
    }

    // ---- poller block (gb == NBLK_TOT) ----
    __shared__ int s_any;
    const unsigned int* pw = (const unsigned int*)partials;  // 7216 words
    for (;;) {
        if (tid == 0) s_any = 0;
        __syncthreads();
        bool any = false;
        for (int w = tid; w < NBLK_TOT * 2; w += 256) {
            const unsigned int v = __hip_atomic_load(
                pw + w, __ATOMIC_RELAXED, __HIP_MEMORY_SCOPE_AGENT);
            any |= (v == SENT);
        }
        if (any) s_any = 1;            // benign race: all writers store 1
        __syncthreads();
        if (!s_any) break;
        __builtin_amdgcn_s_sleep(16);
    }

    // all slots final: classify-reduce (r12 finalize, atomic relaxed loads)
    float n0 = 0.f, d0 = 0.f, n1 = 0.f, d1 = 0.f, n2 = 0.f, d2 = 0.f;
    for (int p = tid; p < NBLK_TOT; p += 256) {
        const float nx = __hip_atomic_load(partials + 2 * p,
                                           __ATOMIC_RELAXED, __HIP_MEMORY_SCOPE_AGENT);
        const float dx = __hip_atomic_load(partials + 2 * p + 1,
                                           __ATOMIC_RELAXED, __HIP_MEMORY_SCOPE_AGENT);
        if (p < NBLK0)              { n0 += nx; d0 += dx; }
        else if (p < NBLK0 + NBLK1) { n1 += nx; d1 += dx; }
        else                        { n2 += nx; d2 += dx; }
    }

    #pragma unroll
    for (int off = 32; off > 0; off >>= 1) {
        n0 += __shfl_down(n0, off);  d0 += __shfl_down(d0, off);
        n1 += __shfl_down(n1, off);  d1 += __shfl_down(d1, off);
        n2 += __shfl_down(n2, off);  d2 += __shfl_down(d2, off);
    }
    __shared__ float s[4][6];
    if ((tid & 63) == 0) {
        const int w = tid >> 6;
        s[w][0] = n0; s[w][1] = d0; s[w][2] = n1;
        s[w][3] = d1; s[w][4] = n2; s[w][5] = d2;
    }
    __syncthreads();
    if (tid == 0) {
        float a[6];
        #pragma unroll
        for (int q = 0; q < 6; ++q)
            a[q] = s[0][q] + s[1][q] + s[2][q] + s[3][q];
        float loss = 0.0f;
        loss += -2.0f * a[0] / fmaxf(a[1], 1e-6f);
        loss += -2.0f * a[2] / fmaxf(a[3], 1e-6f);
        loss += -2.0f * a[4] / fmaxf(a[5], 1e-6f);
        out[0] = loss;
    }
}

extern "C" void kernel_launch(void* const* d_in, const int* in_sizes, int n_in,
                              void* d_out, int out_size, void* d_ws, size_t ws_size,
                              hipStream_t stream)
{
    const float* pred0 = (const float*)d_in[0];
    const int*   tgt0  = (const int*)  d_in[1];
    const float* W0    = (const float*)d_in[2];
    const float* b0    = (const float*)d_in[3];
    const float* pred1 = (const float*)d_in[4];
    const int*   tgt1  = (const int*)  d_in[5];
    const float* W1    = (const float*)d_in[6];
    const float* b1    = (const float*)d_in[7];
    const float* pred2 = (const float*)d_in[8];
    const int*   tgt2  = (const int*)  d_in[9];
    const float* W2    = (const float*)d_in[10];
    const float* b2    = (const float*)d_in[11];

    float* out      = (float*)d_out;
    float* partials = (float*)d_ws;   // 3608 (num,den) pairs

    // sentinel-fill: 0xFF bytes -> 0xFFFFFFFF words (-NaN, unreachable)
    hipMemsetAsync(partials, 0xFF, NBLK_TOT * 2 * sizeof(float), stream);

    fused_kernel<<<NBLK_TOT + 1, 256, 0, stream>>>(
        pred0, tgt0, W0, b0, pred1, tgt1, W1, b1, pred2, tgt2, W2, b2,
        partials, out);
}

// Round 16
// 18.776 us; speedup vs baseline: 3.6091x; 1.5573x over previous
//
#include <hip/hip_runtime.h>
#include <hip/hip_bf16.h>

// StackedPyrHourGlassLoss — round 16 (= round 12/15 design; r15 was an infra
// flake). Final structure: 2-node graph [stage 3608 blocks] -> [finalize
// 1 block]. All single-node alternatives measured WORSE on gfx950 due to
// non-coherent per-XCD L2s making any cross-block visibility guarantee
// cost more than a dependent graph node:
//   r5  release-RMW chain        77 µs
//   r11 spread release-RMW       77 µs
//   r13 cooperative grid.sync    50 µs
//   r14 relaxed-store + sentinel 29 µs
// Stage: validity + embedding via blockIdx-uniform scalar loads (no LDS, no
// barrier on the 94% invalid path); fast sigmoid (v_exp+v_rcp); finalize:
// 512 threads, float4 level-pure loads.

constexpr int NBATCH = 2;
constexpr int EMB = 32;
constexpr int TGTC = 9;      // 1 gt + 8 affinity channels
constexpr int PZ = 5, PY = 15, PX = 15;
constexpr int P = PZ * PY * PX;   // 1125

constexpr int NBLK0 = NBATCH * 4 * 17 * 17;  // 2312
constexpr int NBLK1 = NBATCH * 4 * 9 * 9;    // 648
constexpr int NBLK2 = NBATCH * 4 * 9 * 9;    // 648
constexpr int NBLK_TOT = NBLK0 + NBLK1 + NBLK2;  // 3608

template <int D, int H, int W,
          int NB0, int NBH, int NBW,
          int SH, int SW,
          int DH, int DWIN,
          int OFFZ, int OFFY, int OFFX,
          int AFFB>
__device__ __forceinline__
void level_body(const int lbid,
                const float* __restrict__ pred,
                const int* __restrict__ tgt,
                const float* __restrict__ Wm,
                const float* __restrict__ bv,
                float* __restrict__ partials)
{
    const int tid = threadIdx.x;

    int k  = lbid % NBW;
    int t1 = lbid / NBW;
    int j  = t1 % NBH;
    int t2 = t1 / NBH;
    int i  = t2 % NB0;
    int b  = t2 / NB0;

    const int HW = H * W;
    const int CH = D * HW;
    const int zc = OFFZ + i;           // z-stride is 1 at all levels
    const int yc = OFFY + j * SH;
    const int xc = OFFX + k * SW;
    const int cidx = zc * HW + yc * W + xc;

    // ---- validity: all operands blockIdx-uniform -> scalar loads, no LDS,
    //      no barrier. Every thread computes the same result in registers.
    const int c = tgt[b * TGTC * CH + cidx];
    bool allaff = true;
    #pragma unroll
    for (int ch = 0; ch < 4; ++ch)
        allaff &= (tgt[(b * TGTC + AFFB + ch) * CH + cidx] != 0);
    const bool valid = (c != 0) && allaff;

    if (!valid) {
        if (tid == 0) {
            partials[2 * lbid]     = 0.0f;
            partials[2 * lbid + 1] = 0.0f;
        }
        return;                        // no barrier on the 94% path
    }

    // ---- embedding: 32 uniform loads -> registers (scalar file) ----
    float ev[EMB];
    #pragma unroll
    for (int e = 0; e < EMB; ++e)
        ev[e] = pred[(b * EMB + e) * CH + cidx];

    const int* __restrict__ gtb = tgt + b * TGTC * CH;  // gt channel

    float num = 0.0f, den = 0.0f;
    for (int o = tid; o < P; o += 256) {
        const int pz = o / (PY * PX);
        const int r  = o - pz * (PY * PX);
        const int py = r / PX;
        const int px = r - py * PX;

        float dot = bv[o];
        #pragma unroll
        for (int e = 0; e < EMB; ++e)
            dot = fmaf(ev[e], Wm[e * P + o], dot);
        // fast sigmoid (rel err ~1e-7; threshold 4.7e-2)
        float pp = __builtin_amdgcn_rcpf(1.0f + __expf(-dot));

        const int zb = i + pz;
        const int yb = j * SH + py * DH;
        const int xb = k * SW + px * DWIN;
        bool anyz = false, anyd = false;
        #pragma unroll
        for (int wy = 0; wy < DH; ++wy) {
            #pragma unroll
            for (int wx = 0; wx < DWIN; ++wx) {
                const int g = gtb[zb * HW + (yb + wy) * W + (xb + wx)];
                anyz |= (g == 0);
                anyd |= (g != c);
            }
        }
        float trg = (anyz || !anyd) ? 0.0f : 1.0f;
        if (anyz) pp = 0.0f;

        num = fmaf(pp, trg, num);
        den += pp * pp + trg * trg;
    }

    // wave butterfly then one LDS round across the 4 waves (valid path only)
    #pragma unroll
    for (int off = 32; off > 0; off >>= 1) {
        num += __shfl_xor(num, off);
        den += __shfl_xor(den, off);
    }
    __shared__ float sn[4], sd[4];
    if ((tid & 63) == 0) { sn[tid >> 6] = num; sd[tid >> 6] = den; }
    __syncthreads();
    if (tid == 0) {
        partials[2 * lbid]     = sn[0] + sn[1] + sn[2] + sn[3];
        partials[2 * lbid + 1] = sd[0] + sd[1] + sd[2] + sd[3];
    }
}

__global__ __launch_bounds__(256)
void stage_kernel(const float* __restrict__ pred0, const int* __restrict__ tgt0,
                  const float* __restrict__ W0, const float* __restrict__ b0,
                  const float* __restrict__ pred1, const int* __restrict__ tgt1,
                  const float* __restrict__ W1, const float* __restrict__ b1,
                  const float* __restrict__ pred2, const int* __restrict__ tgt2,
                  const float* __restrict__ W2, const float* __restrict__ b2,
                  float* __restrict__ partials)
{
    const int gb = blockIdx.x;
    if (gb < NBLK0) {
        // lvl0: 8,160,160  nb=(4,17,17) stride=6 dws=4 off=(2,30,30) aff 5..8
        level_body<8, 160, 160, 4, 17, 17, 6, 6, 4, 4, 2, 30, 30, 5>(
            gb, pred0, tgt0, W0, b0, partials);
    } else if (gb < NBLK0 + NBLK1) {
        // lvl1: 8,80,80  nb=(4,9,9) stride=6 dws=2 off=(2,15,15) aff 1..4
        level_body<8, 80, 80, 4, 9, 9, 6, 6, 2, 2, 2, 15, 15, 1>(
            gb - NBLK0, pred1, tgt1, W1, b1, partials + 2 * NBLK0);
    } else {
        // lvl2: 8,40,40  nb=(4,9,9) stride=3 dws=1 off=(2,7,7) aff 1..4
        level_body<8, 40, 40, 4, 9, 9, 3, 3, 1, 1, 2, 7, 7, 1>(
            gb - NBLK0 - NBLK1, pred2, tgt2, W2, b2,
            partials + 2 * (NBLK0 + NBLK1));
    }
}

__global__ __launch_bounds__(512)
void finalize_kernel(const float* __restrict__ partials, float* __restrict__ out)
{
    const int tid = threadIdx.x;

    // 3608 float2 pairs = 1804 float4; level boundaries (2312, 2960) are
    // even pb indices -> every float4 is level-pure.
    constexpr int NF4 = NBLK_TOT / 2;          // 1804
    constexpr int B01 = NBLK0 / 2;             // 1156
    constexpr int B12 = (NBLK0 + NBLK1) / 2;   // 1480

    float n0 = 0.f, d0 = 0.f, n1 = 0.f, d1 = 0.f, n2 = 0.f, d2 = 0.f;
    const float4* p4 = (const float4*)partials;
    for (int p = tid; p < NF4; p += 512) {
        const float4 v = p4[p];
        if (p < B01)      { n0 += v.x + v.z; d0 += v.y + v.w; }
        else if (p < B12) { n1 += v.x + v.z; d1 += v.y + v.w; }
        else              { n2 += v.x + v.z; d2 += v.y + v.w; }
    }

    #pragma unroll
    for (int off = 32; off > 0; off >>= 1) {
        n0 += __shfl_down(n0, off);  d0 += __shfl_down(d0, off);
        n1 += __shfl_down(n1, off);  d1 += __shfl_down(d1, off);
        n2 += __shfl_down(n2, off);  d2 += __shfl_down(d2, off);
    }
    __shared__ float s[8][6];
    if ((tid & 63) == 0) {
        const int w = tid >> 6;
        s[w][0] = n0; s[w][1] = d0; s[w][2] = n1;
        s[w][3] = d1; s[w][4] = n2; s[w][5] = d2;
    }
    __syncthreads();
    if (tid == 0) {
        float acc[6];
        #pragma unroll
        for (int q = 0; q < 6; ++q) {
            acc[q] = s[0][q];
            #pragma unroll
            for (int w = 1; w < 8; ++w) acc[q] += s[w][q];
        }
        float loss = 0.0f;
        loss += -2.0f * acc[0] / fmaxf(acc[1], 1e-6f);
        loss += -2.0f * acc[2] / fmaxf(acc[3], 1e-6f);
        loss += -2.0f * acc[4] / fmaxf(acc[5], 1e-6f);
        out[0] = loss;
    }
}

extern "C" void kernel_launch(void* const* d_in, const int* in_sizes, int n_in,
                              void* d_out, int out_size, void* d_ws, size_t ws_size,
                              hipStream_t stream)
{
    const float* pred0 = (const float*)d_in[0];
    const int*   tgt0  = (const int*)  d_in[1];
    const float* W0    = (const float*)d_in[2];
    const float* b0    = (const float*)d_in[3];
    const float* pred1 = (const float*)d_in[4];
    const int*   tgt1  = (const int*)  d_in[5];
    const float* W1    = (const float*)d_in[6];
    const float* b1    = (const float*)d_in[7];
    const float* pred2 = (const float*)d_in[8];
    const int*   tgt2  = (const int*)  d_in[9];
    const float* W2    = (const float*)d_in[10];
    const float* b2    = (const float*)d_in[11];

    float* out      = (float*)d_out;
    float* partials = (float*)d_ws;   // 3608 (num,den) pairs

    stage_kernel<<<NBLK_TOT, 256, 0, stream>>>(
        pred0, tgt0, W0, b0, pred1, tgt1, W1, b1, pred2, tgt2, W2, b2,
        partials);
    finalize_kernel<<<1, 512, 0, stream>>>(partials, out);
}